// Round 1
// baseline (182.670 us; speedup 1.0000x reference)
//
#include <hip/hip_runtime.h>

#define DMODEL 768
#define NHEAD  12
#define DK     64
#define NB     2
#define SEQ    2048
#define NTOK   (NB*SEQ)     // 4096
#define KITERS (DMODEL/32)  // 24

using bf16x8 = __attribute__((ext_vector_type(8))) short;
using f32x4  = __attribute__((ext_vector_type(4))) float;

__device__ __forceinline__ unsigned short f2bf(float f) {
  unsigned int u = __builtin_bit_cast(unsigned int, f);
  u = (u + 0x7FFFu + ((u >> 16) & 1u)) >> 16;
  return (unsigned short)u;
}

// ---------------- f32 -> bf16 convert (query/key/value) ----------------
__global__ __launch_bounds__(256) void convx_kernel(
    const float* __restrict__ q, const float* __restrict__ k, const float* __restrict__ v,
    unsigned short* __restrict__ oq, unsigned short* __restrict__ ok, unsigned short* __restrict__ ov) {
  const float* in = blockIdx.z == 0 ? q : (blockIdx.z == 1 ? k : v);
  unsigned short* out = blockIdx.z == 0 ? oq : (blockIdx.z == 1 ? ok : ov);
  size_t i = ((size_t)blockIdx.x * 256 + threadIdx.x) * 4;
  float4 f = *(const float4*)(in + i);
  ushort4 o;
  o.x = f2bf(f.x); o.y = f2bf(f.y); o.z = f2bf(f.z); o.w = f2bf(f.w);
  *(ushort4*)(out + i) = o;
}

// ---------------- W (f32, [K][N]) -> W^T (bf16, [N][K]) ----------------
__global__ __launch_bounds__(256) void wtrans_kernel(
    const float* __restrict__ w0, const float* __restrict__ w1,
    const float* __restrict__ w2, const float* __restrict__ w3,
    unsigned short* __restrict__ o0, unsigned short* __restrict__ o1,
    unsigned short* __restrict__ o2, unsigned short* __restrict__ o3) {
  __shared__ unsigned short tile[64][80];
  int z = blockIdx.z;
  const float* in = z == 0 ? w0 : z == 1 ? w1 : z == 2 ? w2 : w3;
  unsigned short* out = z == 0 ? o0 : z == 1 ? o1 : z == 2 ? o2 : o3;
  int c0 = blockIdx.x * 64, r0 = blockIdx.y * 64;
  int t = threadIdx.x, row = t >> 2, ch = t & 3;
#pragma unroll
  for (int j4 = 0; j4 < 4; ++j4) {
    float4 f = *(const float4*)(in + (size_t)(r0 + row) * DMODEL + c0 + ch * 16 + j4 * 4);
    tile[row][ch * 16 + j4 * 4 + 0] = f2bf(f.x);
    tile[row][ch * 16 + j4 * 4 + 1] = f2bf(f.y);
    tile[row][ch * 16 + j4 * 4 + 2] = f2bf(f.z);
    tile[row][ch * 16 + j4 * 4 + 3] = f2bf(f.w);
  }
  __syncthreads();
  uint4 wA, wB;
  unsigned short* ta = (unsigned short*)&wA;
  unsigned short* tb = (unsigned short*)&wB;
#pragma unroll
  for (int j = 0; j < 8; ++j) { ta[j] = tile[ch * 16 + j][row]; tb[j] = tile[ch * 16 + 8 + j][row]; }
  unsigned short* ob = out + (size_t)(c0 + row) * DMODEL + r0 + ch * 16;
  *(uint4*)ob = wA;
  *(uint4*)(ob + 8) = wB;
}

// ---------------- V [B,H,S,DK] -> V^T [B,H,DK,S] (bf16) ----------------
__global__ __launch_bounds__(256) void vtrans_kernel(
    const unsigned short* __restrict__ in, unsigned short* __restrict__ out) {
  __shared__ unsigned short tile[64][80];
  int z = blockIdx.y;  // head index b*12+h
  const unsigned short* ip = in + (size_t)z * SEQ * DK;
  unsigned short* op = out + (size_t)z * DK * SEQ;
  int r0 = blockIdx.x * 64;
  int t = threadIdx.x, row = t >> 2, ch = t & 3;
  uint4 a = *(const uint4*)(ip + (size_t)(r0 + row) * DK + ch * 16);
  uint4 b = *(const uint4*)(ip + (size_t)(r0 + row) * DK + ch * 16 + 8);
  *(uint4*)&tile[row][ch * 16] = a;
  *(uint4*)&tile[row][ch * 16 + 8] = b;
  __syncthreads();
  uint4 wA, wB;
  unsigned short* ta = (unsigned short*)&wA;
  unsigned short* tb = (unsigned short*)&wB;
#pragma unroll
  for (int j = 0; j < 8; ++j) { ta[j] = tile[ch * 16 + j][row]; tb[j] = tile[ch * 16 + 8 + j][row]; }
  unsigned short* ob = op + (size_t)row * SEQ + r0 + ch * 16;
  *(uint4*)ob = wA;
  *(uint4*)(ob + 8) = wB;
}

// ---------------- 128x128 tile bf16 GEMM body (C = A @ BT^T) ----------------
__device__ __forceinline__ void gemm_body(
    const unsigned short* __restrict__ A, const unsigned short* __restrict__ BT,
    unsigned short* As, unsigned short* Bs, int rowbase, int colbase, f32x4 acc[4][4]) {
  int t = threadIdx.x;
  int lane = t & 63, wave = t >> 6;
  int wr = wave >> 1, wc = wave & 1;
  int l16 = lane & 15, lk = lane >> 4;
  for (int kt = 0; kt < KITERS; ++kt) {
#pragma unroll
    for (int ch = t; ch < 512; ch += 256) {
      int row = ch >> 2, sub = ch & 3;
      uint4 va = *(const uint4*)(A + (size_t)(rowbase + row) * DMODEL + kt * 32 + sub * 8);
      uint4 vb = *(const uint4*)(BT + (size_t)(colbase + row) * DMODEL + kt * 32 + sub * 8);
      int swz = (sub ^ ((row >> 1) & 3)) << 4;
      *(uint4*)((char*)As + row * 64 + swz) = va;
      *(uint4*)((char*)Bs + row * 64 + swz) = vb;
    }
    __syncthreads();
    bf16x8 a[4], b[4];
#pragma unroll
    for (int m = 0; m < 4; ++m) {
      int row = wr * 64 + m * 16 + l16;
      a[m] = *(bf16x8*)((char*)As + row * 64 + ((lk ^ ((row >> 1) & 3)) << 4));
    }
#pragma unroll
    for (int n = 0; n < 4; ++n) {
      int row = wc * 64 + n * 16 + l16;
      b[n] = *(bf16x8*)((char*)Bs + row * 64 + ((lk ^ ((row >> 1) & 3)) << 4));
    }
#pragma unroll
    for (int m = 0; m < 4; ++m)
#pragma unroll
      for (int n = 0; n < 4; ++n)
        acc[m][n] = __builtin_amdgcn_mfma_f32_16x16x32_bf16(a[m], b[n], acc[m][n], 0, 0, 0);
    __syncthreads();
  }
}

struct QKVArgs {
  const unsigned short* A[3];
  const unsigned short* BT[3];
  const float* bias[3];
  unsigned short* out[3];
};

// QKV projections: Y = X @ W + b, scattered to [B,H,S,DK] bf16
__global__ __launch_bounds__(256) void gemm_qkv_kernel(QKVArgs ga) {
  __shared__ unsigned short As[128 * 32];
  __shared__ unsigned short Bs[128 * 32];
  int z = blockIdx.z;
  int rowbase = blockIdx.x * 128, colbase = blockIdx.y * 128;
  f32x4 acc[4][4];
#pragma unroll
  for (int m = 0; m < 4; ++m)
#pragma unroll
    for (int n = 0; n < 4; ++n) acc[m][n] = (f32x4){0.f, 0.f, 0.f, 0.f};
  gemm_body(ga.A[z], ga.BT[z], As, Bs, rowbase, colbase, acc);
  const float* bias = ga.bias[z];
  unsigned short* out = ga.out[z];
  int lane = threadIdx.x & 63, wave = threadIdx.x >> 6;
  int wr = wave >> 1, wc = wave & 1, l16 = lane & 15, lk = lane >> 4;
#pragma unroll
  for (int n = 0; n < 4; ++n) {
    int gcol = colbase + wc * 64 + n * 16 + l16;
    float bv = bias[gcol];
    int h = gcol >> 6, d = gcol & 63;
#pragma unroll
    for (int m = 0; m < 4; ++m) {
      int growb = rowbase + wr * 64 + m * 16 + lk * 4;
#pragma unroll
      for (int i = 0; i < 4; ++i) {
        int grow = growb + i;
        int b = grow >> 11, s = grow & 2047;
        out[((size_t)(b * NHEAD + h) * SEQ + s) * DK + d] = f2bf(acc[m][n][i] + bv);
      }
    }
  }
}

// Output projection: out = AO @ Wo + bo, f32 result
__global__ __launch_bounds__(256) void gemm_o_kernel(
    const unsigned short* __restrict__ A, const unsigned short* __restrict__ BT,
    const float* __restrict__ bias, float* __restrict__ out) {
  __shared__ unsigned short As[128 * 32];
  __shared__ unsigned short Bs[128 * 32];
  int rowbase = blockIdx.x * 128, colbase = blockIdx.y * 128;
  f32x4 acc[4][4];
#pragma unroll
  for (int m = 0; m < 4; ++m)
#pragma unroll
    for (int n = 0; n < 4; ++n) acc[m][n] = (f32x4){0.f, 0.f, 0.f, 0.f};
  gemm_body(A, BT, As, Bs, rowbase, colbase, acc);
  int lane = threadIdx.x & 63, wave = threadIdx.x >> 6;
  int wr = wave >> 1, wc = wave & 1, l16 = lane & 15, lk = lane >> 4;
#pragma unroll
  for (int n = 0; n < 4; ++n) {
    int gcol = colbase + wc * 64 + n * 16 + l16;
    float bv = bias[gcol];
#pragma unroll
    for (int m = 0; m < 4; ++m) {
      int growb = rowbase + wr * 64 + m * 16 + lk * 4;
#pragma unroll
      for (int i = 0; i < 4; ++i)
        out[(size_t)(growb + i) * DMODEL + gcol] = acc[m][n][i] + bv;
    }
  }
}

// ---------------- flash attention ----------------
// grid (32 qtiles, 24 heads), 4 waves x 16 q-rows, KV block = 64
__global__ __launch_bounds__(256) void flash_kernel(
    const unsigned short* __restrict__ Qh, const unsigned short* __restrict__ Kh,
    const unsigned short* __restrict__ Vt, const int* __restrict__ mask,
    unsigned short* __restrict__ AO) {
  __shared__ unsigned short Ks[64 * 64];
  __shared__ unsigned short Vs[64 * 64];
  __shared__ unsigned short Ps[4][16 * 64];
  int qt = blockIdx.x, bh = blockIdx.y;
  int b = bh / NHEAD, h = bh % NHEAD;
  int t = threadIdx.x, lane = t & 63, wave = t >> 6;
  int l16 = lane & 15, lk = lane >> 4;
  size_t headQ = (size_t)bh * SEQ * DK;
  size_t headV = (size_t)bh * DK * SEQ;
  int qbase = qt * 64 + wave * 16;

  bf16x8 aq0 = *(const bf16x8*)(Qh + headQ + (size_t)(qbase + l16) * DK + lk * 8);
  bf16x8 aq1 = *(const bf16x8*)(Qh + headQ + (size_t)(qbase + l16) * DK + 32 + lk * 8);

  float m_i[4] = {-1e30f, -1e30f, -1e30f, -1e30f};
  float l_i[4] = {0.f, 0.f, 0.f, 0.f};
  f32x4 o[4];
#pragma unroll
  for (int n = 0; n < 4; ++n) o[n] = (f32x4){0.f, 0.f, 0.f, 0.f};

  for (int kt = 0; kt < SEQ / 64; ++kt) {
#pragma unroll
    for (int ch = t; ch < 512; ch += 256) {
      int row = ch >> 3, sub = ch & 7;
      uint4 vk = *(const uint4*)(Kh + headQ + (size_t)(kt * 64 + row) * DK + sub * 8);
      uint4 vv = *(const uint4*)(Vt + headV + (size_t)row * SEQ + kt * 64 + sub * 8);
      int byt = (row * 128 + sub * 16) ^ ((row & 7) << 4);
      *(uint4*)((char*)Ks + byt) = vk;
      *(uint4*)((char*)Vs + byt) = vv;
    }
    __syncthreads();

    // scores S = Q K^T  (per wave: 16 q-rows x 64 keys)
    f32x4 s[4];
#pragma unroll
    for (int n = 0; n < 4; ++n) {
      int key = n * 16 + l16;
      bf16x8 b0 = *(bf16x8*)((char*)Ks + ((key * 128 + lk * 16) ^ ((key & 7) << 4)));
      bf16x8 b1 = *(bf16x8*)((char*)Ks + ((key * 128 + 64 + lk * 16) ^ ((key & 7) << 4)));
      f32x4 z = (f32x4){0.f, 0.f, 0.f, 0.f};
      z = __builtin_amdgcn_mfma_f32_16x16x32_bf16(aq0, b0, z, 0, 0, 0);
      z = __builtin_amdgcn_mfma_f32_16x16x32_bf16(aq1, b1, z, 0, 0, 0);
      s[n] = z;
    }

    // scale + mask
    int mbase = b * SEQ + kt * 64;
    float sc[4][4];
#pragma unroll
    for (int n = 0; n < 4; ++n) {
      int mv = mask[mbase + n * 16 + l16];
#pragma unroll
      for (int i = 0; i < 4; ++i) sc[n][i] = mv ? s[n][i] * 0.125f : -1e9f;
    }

    // row max (reduce over 16 lanes within group)
    float rmax[4];
#pragma unroll
    for (int i = 0; i < 4; ++i)
      rmax[i] = fmaxf(fmaxf(sc[0][i], sc[1][i]), fmaxf(sc[2][i], sc[3][i]));
#pragma unroll
    for (int off = 8; off; off >>= 1)
#pragma unroll
      for (int i = 0; i < 4; ++i) rmax[i] = fmaxf(rmax[i], __shfl_xor(rmax[i], off));

    // online softmax update
    float p[4][4], rsum[4];
#pragma unroll
    for (int i = 0; i < 4; ++i) {
      float mn = fmaxf(m_i[i], rmax[i]);
      float corr = __expf(m_i[i] - mn);
      float su = 0.f;
#pragma unroll
      for (int n = 0; n < 4; ++n) { p[n][i] = __expf(sc[n][i] - mn); su += p[n][i]; }
      rsum[i] = su;
      l_i[i] *= corr;
      m_i[i] = mn;
#pragma unroll
      for (int t4 = 0; t4 < 4; ++t4) o[t4][i] *= corr;
    }
#pragma unroll
    for (int off = 8; off; off >>= 1)
#pragma unroll
      for (int i = 0; i < 4; ++i) rsum[i] += __shfl_xor(rsum[i], off);
#pragma unroll
    for (int i = 0; i < 4; ++i) l_i[i] += rsum[i];

    // P -> wave-private LDS (C-layout -> A-layout bounce)
    unsigned short* pw = &Ps[wave][0];
#pragma unroll
    for (int n = 0; n < 4; ++n)
#pragma unroll
      for (int i = 0; i < 4; ++i) {
        int prow = lk * 4 + i, pcol = n * 16 + l16;
        int byt = (prow * 128 + pcol * 2) ^ ((prow & 7) << 4);
        *(unsigned short*)((char*)pw + byt) = f2bf(p[n][i]);
      }

    bf16x8 ap0 = *(bf16x8*)((char*)pw + ((l16 * 128 + lk * 16) ^ ((l16 & 7) << 4)));
    bf16x8 ap1 = *(bf16x8*)((char*)pw + ((l16 * 128 + 64 + lk * 16) ^ ((l16 & 7) << 4)));
#pragma unroll
    for (int t4 = 0; t4 < 4; ++t4) {
      int d = t4 * 16 + l16;
      bf16x8 bv0 = *(bf16x8*)((char*)Vs + ((d * 128 + lk * 16) ^ ((d & 7) << 4)));
      bf16x8 bv1 = *(bf16x8*)((char*)Vs + ((d * 128 + 64 + lk * 16) ^ ((d & 7) << 4)));
      o[t4] = __builtin_amdgcn_mfma_f32_16x16x32_bf16(ap0, bv0, o[t4], 0, 0, 0);
      o[t4] = __builtin_amdgcn_mfma_f32_16x16x32_bf16(ap1, bv1, o[t4], 0, 0, 0);
    }
    __syncthreads();
  }

  // epilogue: AO[b, s, h*64+d] = o / l
#pragma unroll
  for (int t4 = 0; t4 < 4; ++t4) {
    int col = h * DK + t4 * 16 + l16;
#pragma unroll
    for (int i = 0; i < 4; ++i) {
      int srow = qbase + lk * 4 + i;
      AO[(size_t)(b * SEQ + srow) * DMODEL + col] = f2bf(o[t4][i] / l_i[i]);
    }
  }
}

extern "C" void kernel_launch(void* const* d_in, const int* in_sizes, int n_in,
                              void* d_out, int out_size, void* d_ws, size_t ws_size,
                              hipStream_t stream) {
  const float* gq  = (const float*)d_in[0];
  const float* gk  = (const float*)d_in[1];
  const float* gv  = (const float*)d_in[2];
  const int* gmask = (const int*)d_in[3];
  const float* gWq = (const float*)d_in[4];
  const float* gbq = (const float*)d_in[5];
  const float* gWk = (const float*)d_in[6];
  const float* gbk = (const float*)d_in[7];
  const float* gWv = (const float*)d_in[8];
  const float* gbv = (const float*)d_in[9];
  const float* gWo = (const float*)d_in[10];
  const float* gbo = (const float*)d_in[11];
  float* out = (float*)d_out;

  char* ws = (char*)d_ws;
  const size_t XSZ = (size_t)NTOK * DMODEL * 2;   // 6 291 456 B
  const size_t WSZ = (size_t)DMODEL * DMODEL * 2; // 1 179 648 B
  unsigned short* Xq  = (unsigned short*)ws; ws += XSZ;
  unsigned short* Xk  = (unsigned short*)ws; ws += XSZ;
  unsigned short* Xv  = (unsigned short*)ws; ws += XSZ;
  unsigned short* WqT = (unsigned short*)ws; ws += WSZ;
  unsigned short* WkT = (unsigned short*)ws; ws += WSZ;
  unsigned short* WvT = (unsigned short*)ws; ws += WSZ;
  unsigned short* WoT = (unsigned short*)ws; ws += WSZ;
  unsigned short* Qh  = (unsigned short*)ws; ws += XSZ;
  unsigned short* Kh  = (unsigned short*)ws; ws += XSZ;
  unsigned short* Vh  = (unsigned short*)ws; ws += XSZ;
  unsigned short* Vt  = (unsigned short*)ws; ws += XSZ;
  unsigned short* AO  = (unsigned short*)ws; ws += XSZ;

  convx_kernel<<<dim3(NTOK * DMODEL / 1024, 1, 3), 256, 0, stream>>>(gq, gk, gv, Xq, Xk, Xv);
  wtrans_kernel<<<dim3(12, 12, 4), 256, 0, stream>>>(gWq, gWk, gWv, gWo, WqT, WkT, WvT, WoT);

  QKVArgs ga;
  ga.A[0] = Xq; ga.A[1] = Xk; ga.A[2] = Xv;
  ga.BT[0] = WqT; ga.BT[1] = WkT; ga.BT[2] = WvT;
  ga.bias[0] = gbq; ga.bias[1] = gbk; ga.bias[2] = gbv;
  ga.out[0] = Qh; ga.out[1] = Kh; ga.out[2] = Vh;
  gemm_qkv_kernel<<<dim3(32, 6, 3), 256, 0, stream>>>(ga);

  vtrans_kernel<<<dim3(SEQ / 64, NB * NHEAD), 256, 0, stream>>>(Vh, Vt);
  flash_kernel<<<dim3(SEQ / 64, NB * NHEAD), 256, 0, stream>>>(Qh, Kh, Vt, gmask, AO);
  gemm_o_kernel<<<dim3(32, 6), 256, 0, stream>>>(AO, WoT, gbo, out);
}

// Round 2
// 133.643 us; speedup vs baseline: 1.3668x; 1.3668x over previous
//
#include <hip/hip_runtime.h>

#define DMODEL 768
#define NHEAD  12
#define DK     64
#define NB     2
#define SEQ    2048
#define NTOK   (NB*SEQ)     // 4096
#define GKIT   (DMODEL/32)  // 24

using bf16x8 = __attribute__((ext_vector_type(8))) short;
using f32x4  = __attribute__((ext_vector_type(4))) float;

typedef __attribute__((address_space(1))) const unsigned int gas_u32;
typedef __attribute__((address_space(3))) unsigned int las_u32;

__device__ __forceinline__ void gload_lds16(const void* g, void* l) {
  __builtin_amdgcn_global_load_lds((gas_u32*)g, (las_u32*)l, 16, 0, 0);
}

__device__ __forceinline__ unsigned short f2bf(float f) {
  unsigned int u = __builtin_bit_cast(unsigned int, f);
  u = (u + 0x7FFFu + ((u >> 16) & 1u)) >> 16;
  return (unsigned short)u;
}

__device__ __forceinline__ unsigned cvtpk_bf16(float lo, float hi) {
  unsigned r;
  asm volatile("v_cvt_pk_bf16_f32 %0, %1, %2" : "=v"(r) : "v"(lo), "v"(hi));
  return r;
}

// ---------------- f32 -> bf16 convert (query/key/value) ----------------
__global__ __launch_bounds__(256) void convx_kernel(
    const float* __restrict__ q, const float* __restrict__ k, const float* __restrict__ v,
    unsigned short* __restrict__ oq, unsigned short* __restrict__ ok, unsigned short* __restrict__ ov) {
  const float* in = blockIdx.z == 0 ? q : (blockIdx.z == 1 ? k : v);
  unsigned short* out = blockIdx.z == 0 ? oq : (blockIdx.z == 1 ? ok : ov);
  size_t i = ((size_t)blockIdx.x * 256 + threadIdx.x) * 4;
  float4 f = *(const float4*)(in + i);
  ushort4 o;
  o.x = f2bf(f.x); o.y = f2bf(f.y); o.z = f2bf(f.z); o.w = f2bf(f.w);
  *(ushort4*)(out + i) = o;
}

// ---------------- W (f32, [K][N]) -> W^T (bf16, [N][K]) + mask bias ----------------
__global__ __launch_bounds__(256) void wtrans_kernel(
    const float* __restrict__ w0, const float* __restrict__ w1,
    const float* __restrict__ w2, const float* __restrict__ w3,
    unsigned short* __restrict__ o0, unsigned short* __restrict__ o1,
    unsigned short* __restrict__ o2, unsigned short* __restrict__ o3,
    const int* __restrict__ mask, float* __restrict__ maskbias) {
  __shared__ unsigned short tile[64][80];
  int z = blockIdx.z;
  if (z == 4) {
    if (blockIdx.x == 0 && blockIdx.y == 0) {
      for (int i = threadIdx.x; i < NB * SEQ; i += 256)
        maskbias[i] = mask[i] ? 0.f : -1.4426950408889634e9f;  // -1e9 * log2(e)
    }
    return;
  }
  const float* in = z == 0 ? w0 : z == 1 ? w1 : z == 2 ? w2 : w3;
  unsigned short* out = z == 0 ? o0 : z == 1 ? o1 : z == 2 ? o2 : o3;
  int c0 = blockIdx.x * 64, r0 = blockIdx.y * 64;
  int t = threadIdx.x, row = t >> 2, ch = t & 3;
#pragma unroll
  for (int j4 = 0; j4 < 4; ++j4) {
    float4 f = *(const float4*)(in + (size_t)(r0 + row) * DMODEL + c0 + ch * 16 + j4 * 4);
    tile[row][ch * 16 + j4 * 4 + 0] = f2bf(f.x);
    tile[row][ch * 16 + j4 * 4 + 1] = f2bf(f.y);
    tile[row][ch * 16 + j4 * 4 + 2] = f2bf(f.z);
    tile[row][ch * 16 + j4 * 4 + 3] = f2bf(f.w);
  }
  __syncthreads();
  uint4 wA, wB;
  unsigned short* ta = (unsigned short*)&wA;
  unsigned short* tb = (unsigned short*)&wB;
#pragma unroll
  for (int j = 0; j < 8; ++j) { ta[j] = tile[ch * 16 + j][row]; tb[j] = tile[ch * 16 + 8 + j][row]; }
  unsigned short* ob = out + (size_t)(c0 + row) * DMODEL + r0 + ch * 16;
  *(uint4*)ob = wA;
  *(uint4*)(ob + 8) = wB;
}

// ---------------- V [B,H,S,DK] -> V^T [B,H,DK,S] (bf16) ----------------
__global__ __launch_bounds__(256) void vtrans_kernel(
    const unsigned short* __restrict__ in, unsigned short* __restrict__ out) {
  __shared__ unsigned short tile[64][80];
  int z = blockIdx.y;
  const unsigned short* ip = in + (size_t)z * SEQ * DK;
  unsigned short* op = out + (size_t)z * DK * SEQ;
  int r0 = blockIdx.x * 64;
  int t = threadIdx.x, row = t >> 2, ch = t & 3;
  uint4 a = *(const uint4*)(ip + (size_t)(r0 + row) * DK + ch * 16);
  uint4 b = *(const uint4*)(ip + (size_t)(r0 + row) * DK + ch * 16 + 8);
  *(uint4*)&tile[row][ch * 16] = a;
  *(uint4*)&tile[row][ch * 16 + 8] = b;
  __syncthreads();
  uint4 wA, wB;
  unsigned short* ta = (unsigned short*)&wA;
  unsigned short* tb = (unsigned short*)&wB;
#pragma unroll
  for (int j = 0; j < 8; ++j) { ta[j] = tile[ch * 16 + j][row]; tb[j] = tile[ch * 16 + 8 + j][row]; }
  unsigned short* ob = op + (size_t)row * SEQ + r0 + ch * 16;
  *(uint4*)ob = wA;
  *(uint4*)(ob + 8) = wB;
}

// ---------------- m97-style GEMM core: 128x128 tile, BK=32, async dbuf ----------------
__device__ __forceinline__ void gemm_stage(const unsigned short* A, const unsigned short* BT,
    unsigned short* As, unsigned short* Bs, int rowbase, int colbase, int kt, int wave, int lane) {
  int rb = wave * 32;
  int r = lane >> 2, c = lane & 3;
#pragma unroll
  for (int iss = 0; iss < 2; ++iss) {
    int row = rb + iss * 16 + r;
    gload_lds16(A + (size_t)(rowbase + row) * DMODEL + kt * 32 + c * 8, As + (rb + iss * 16) * 32);
    gload_lds16(BT + (size_t)(colbase + row) * DMODEL + kt * 32 + c * 8, Bs + (rb + iss * 16) * 32);
  }
}

__device__ __forceinline__ bf16x8 fragr(const unsigned short* S, int row, int lk) {
  return *(const bf16x8*)((const char*)S + row * 64 + lk * 16);
}

__device__ __forceinline__ void gemm_core(const unsigned short* A, const unsigned short* BT,
    unsigned short (*As)[128 * 32], unsigned short (*Bs)[128 * 32],
    int rowbase, int colbase, f32x4 acc[4][4]) {
  int t = threadIdx.x, lane = t & 63, wave = t >> 6;
  int wr = wave >> 1, wc = wave & 1, l16 = lane & 15, lk = lane >> 4;
  gemm_stage(A, BT, As[0], Bs[0], rowbase, colbase, 0, wave, lane);
  __syncthreads();
  for (int kt = 0; kt < GKIT; ++kt) {
    int cur = kt & 1;
    if (kt < GKIT - 1)
      gemm_stage(A, BT, As[cur ^ 1], Bs[cur ^ 1], rowbase, colbase, kt + 1, wave, lane);
    bf16x8 a[4], bb[4];
#pragma unroll
    for (int m = 0; m < 4; ++m) a[m] = fragr(As[cur], wr * 64 + m * 16 + l16, lk);
#pragma unroll
    for (int n = 0; n < 4; ++n) bb[n] = fragr(Bs[cur], wc * 64 + n * 16 + l16, lk);
    __builtin_amdgcn_s_setprio(1);
#pragma unroll
    for (int m = 0; m < 4; ++m)
#pragma unroll
      for (int n = 0; n < 4; ++n)
        acc[m][n] = __builtin_amdgcn_mfma_f32_16x16x32_bf16(a[m], bb[n], acc[m][n], 0, 0, 0);
    __builtin_amdgcn_s_setprio(0);
    __syncthreads();
  }
}

struct QKVArgs {
  const unsigned short* A[3];
  const unsigned short* BT[3];
  const float* bias[3];
  unsigned short* out[3];
  float scale[3];
};

__global__ __launch_bounds__(256) void gemm_qkv_kernel(QKVArgs ga) {
  __shared__ unsigned short As[2][128 * 32];
  __shared__ unsigned short Bs[2][128 * 32];
  int z = blockIdx.z;
  int rowbase = blockIdx.x * 128, colbase = blockIdx.y * 128;
  f32x4 acc[4][4];
#pragma unroll
  for (int m = 0; m < 4; ++m)
#pragma unroll
    for (int n = 0; n < 4; ++n) acc[m][n] = (f32x4){0.f, 0.f, 0.f, 0.f};
  gemm_core(ga.A[z], ga.BT[z], As, Bs, rowbase, colbase, acc);
  const float* bias = ga.bias[z];
  unsigned short* out = ga.out[z];
  float scale = ga.scale[z];
  int lane = threadIdx.x & 63, wave = threadIdx.x >> 6;
  int wr = wave >> 1, wc = wave & 1, l16 = lane & 15, lk = lane >> 4;
#pragma unroll
  for (int n = 0; n < 4; ++n) {
    int gcol = colbase + wc * 64 + n * 16 + l16;
    float bv = bias[gcol];
    int h = gcol >> 6, d = gcol & 63;
#pragma unroll
    for (int m = 0; m < 4; ++m) {
      int growb = rowbase + wr * 64 + m * 16 + lk * 4;
#pragma unroll
      for (int i = 0; i < 4; ++i) {
        int grow = growb + i;
        int b = grow >> 11, s = grow & 2047;
        out[((size_t)(b * NHEAD + h) * SEQ + s) * DK + d] = f2bf((acc[m][n][i] + bv) * scale);
      }
    }
  }
}

__global__ __launch_bounds__(256) void gemm_o_kernel(
    const unsigned short* __restrict__ A, const unsigned short* __restrict__ BT,
    const float* __restrict__ bias, float* __restrict__ out) {
  __shared__ unsigned short As[2][128 * 32];
  __shared__ unsigned short Bs[2][128 * 32];
  int rowbase = blockIdx.x * 128, colbase = blockIdx.y * 128;
  f32x4 acc[4][4];
#pragma unroll
  for (int m = 0; m < 4; ++m)
#pragma unroll
    for (int n = 0; n < 4; ++n) acc[m][n] = (f32x4){0.f, 0.f, 0.f, 0.f};
  gemm_core(A, BT, As, Bs, rowbase, colbase, acc);
  int lane = threadIdx.x & 63, wave = threadIdx.x >> 6;
  int wr = wave >> 1, wc = wave & 1, l16 = lane & 15, lk = lane >> 4;
#pragma unroll
  for (int n = 0; n < 4; ++n) {
    int gcol = colbase + wc * 64 + n * 16 + l16;
    float bv = bias[gcol];
#pragma unroll
    for (int m = 0; m < 4; ++m) {
      int growb = rowbase + wr * 64 + m * 16 + lk * 4;
#pragma unroll
      for (int i = 0; i < 4; ++i)
        out[(size_t)(growb + i) * DMODEL + gcol] = acc[m][n][i] + bv;
    }
  }
}

// ---------------- flash attention ----------------
// Q pre-scaled by 0.125*log2e; maskbias additive in log2 domain.
// Swapped QK^T: lane owns q = qbase+l16; keys distributed as rows.
__global__ __launch_bounds__(256) void flash_kernel(
    const unsigned short* __restrict__ Qh, const unsigned short* __restrict__ Kh,
    const unsigned short* __restrict__ Vt, const float* __restrict__ maskbias,
    unsigned short* __restrict__ AO) {
  __shared__ unsigned short Ks[2][64 * 64];
  __shared__ unsigned short Vs[2][64 * 64];
  __shared__ unsigned short Ps[4][16 * 64];

  // XCD swizzle: 3 heads per XCD chunk (768 = 8 * 96)
  int orig = blockIdx.x;
  int xcd = orig & 7, idx = orig >> 3;
  int bh = xcd * 3 + (idx >> 5);
  int qt = idx & 31;
  int b = bh / NHEAD, h = bh % NHEAD;

  int t = threadIdx.x, lane = t & 63, wave = t >> 6;
  int l16 = lane & 15, lk = lane >> 4;
  size_t headQ = (size_t)bh * SEQ * DK;
  size_t headV = (size_t)bh * DK * SEQ;
  int qbase = qt * 64 + wave * 16;

  const unsigned short* Kg = Kh + headQ;
  const unsigned short* Vg = Vt + headV;
  const float* mb = maskbias + b * SEQ;

  bf16x8 aq0 = *(const bf16x8*)(Qh + headQ + (size_t)(qbase + l16) * DK + lk * 8);
  bf16x8 aq1 = *(const bf16x8*)(Qh + headQ + (size_t)(qbase + l16) * DK + 32 + lk * 8);

  float m_i = -1e30f, l_i = 0.f;
  f32x4 o[4];
#pragma unroll
  for (int n = 0; n < 4; ++n) o[n] = (f32x4){0.f, 0.f, 0.f, 0.f};

  int srow = lane >> 3, sch = lane & 7;
  int rb = wave * 16;

  // stage tile 0 (linear LDS dest, inverse-swizzled global source)
#pragma unroll
  for (int iss = 0; iss < 2; ++iss) {
    int row = rb + iss * 8 + srow;
    gload_lds16(Kg + (size_t)row * DK + ((sch ^ (row & 7)) << 3), &Ks[0][(rb + iss * 8) * 64]);
    gload_lds16(Vg + (size_t)row * SEQ + ((sch ^ (row & 7)) << 3), &Vs[0][(rb + iss * 8) * 64]);
  }
  __syncthreads();

  for (int kt = 0; kt < SEQ / 64; ++kt) {
    int cur = kt & 1;
    if (kt < SEQ / 64 - 1) {
#pragma unroll
      for (int iss = 0; iss < 2; ++iss) {
        int row = rb + iss * 8 + srow;
        gload_lds16(Kg + (size_t)((kt + 1) * 64 + row) * DK + ((sch ^ (row & 7)) << 3),
                    &Ks[cur ^ 1][(rb + iss * 8) * 64]);
        gload_lds16(Vg + (size_t)row * SEQ + (kt + 1) * 64 + ((sch ^ (row & 7)) << 3),
                    &Vs[cur ^ 1][(rb + iss * 8) * 64]);
      }
    }

    // QK^T (swapped): sv[n] rows = keys n*16+lk*4+i, col = q = qbase+l16
    const char* kb = (const char*)&Ks[cur][0];
    f32x4 sv[4];
    __builtin_amdgcn_s_setprio(1);
#pragma unroll
    for (int n = 0; n < 4; ++n) {
      f32x4 bias = *(const f32x4*)(mb + kt * 64 + n * 16 + lk * 4);
      int key = n * 16 + l16;
      bf16x8 k0 = *(const bf16x8*)(kb + ((key * 128 + lk * 16) ^ ((key & 7) << 4)));
      bf16x8 k1 = *(const bf16x8*)(kb + ((key * 128 + 64 + lk * 16) ^ ((key & 7) << 4)));
      f32x4 z = __builtin_amdgcn_mfma_f32_16x16x32_bf16(k1, aq1, bias, 0, 0, 0);
      sv[n] = __builtin_amdgcn_mfma_f32_16x16x32_bf16(k0, aq0, z, 0, 0, 0);
    }
    __builtin_amdgcn_s_setprio(0);

    // row max: in-lane tree + 2 shfl (4 lk-groups hold same q)
    float pmax = -3.0e38f;
#pragma unroll
    for (int n = 0; n < 4; ++n)
#pragma unroll
      for (int i = 0; i < 4; ++i) pmax = fmaxf(pmax, sv[n][i]);
    pmax = fmaxf(pmax, __shfl_xor(pmax, 16));
    pmax = fmaxf(pmax, __shfl_xor(pmax, 32));

    // defer-max rescale (THR = 8 in log2 domain)
    if (__any(pmax > m_i + 8.0f)) {
      float mnew = fmaxf(m_i, pmax);
      float corr = exp2f(m_i - mnew);
      l_i *= corr;
      m_i = mnew;
      float c0 = __shfl(corr, lk * 4 + 0);
      float c1 = __shfl(corr, lk * 4 + 1);
      float c2 = __shfl(corr, lk * 4 + 2);
      float c3 = __shfl(corr, lk * 4 + 3);
#pragma unroll
      for (int t4 = 0; t4 < 4; ++t4) {
        o[t4][0] *= c0; o[t4][1] *= c1; o[t4][2] *= c2; o[t4][3] *= c3;
      }
    }

    float p[4][4];
    float su = 0.f;
#pragma unroll
    for (int n = 0; n < 4; ++n)
#pragma unroll
      for (int i = 0; i < 4; ++i) { p[n][i] = exp2f(sv[n][i] - m_i); su += p[n][i]; }
    su += __shfl_xor(su, 16);
    su += __shfl_xor(su, 32);
    l_i += su;

    // pack P -> wave-private LDS (rows = q-within-wave = l16, swizzled)
    unsigned short* pw = &Ps[wave][0];
#pragma unroll
    for (int n = 0; n < 4; ++n) {
      uint2 w;
      w.x = cvtpk_bf16(p[n][0], p[n][1]);
      w.y = cvtpk_bf16(p[n][2], p[n][3]);
      int byt = (l16 * 128 + n * 32 + lk * 8) ^ ((l16 & 7) << 4);
      *(uint2*)((char*)pw + byt) = w;
    }

    bf16x8 ap0 = *(const bf16x8*)((char*)pw + ((l16 * 128 + lk * 16) ^ ((l16 & 7) << 4)));
    bf16x8 ap1 = *(const bf16x8*)((char*)pw + ((l16 * 128 + 64 + lk * 16) ^ ((l16 & 7) << 4)));

    const char* vb = (const char*)&Vs[cur][0];
    __builtin_amdgcn_s_setprio(1);
#pragma unroll
    for (int t4 = 0; t4 < 4; ++t4) {
      int d = t4 * 16 + l16;
      bf16x8 bv0 = *(const bf16x8*)(vb + ((d * 128 + lk * 16) ^ ((d & 7) << 4)));
      bf16x8 bv1 = *(const bf16x8*)(vb + ((d * 128 + 64 + lk * 16) ^ ((d & 7) << 4)));
      o[t4] = __builtin_amdgcn_mfma_f32_16x16x32_bf16(ap0, bv0, o[t4], 0, 0, 0);
      o[t4] = __builtin_amdgcn_mfma_f32_16x16x32_bf16(ap1, bv1, o[t4], 0, 0, 0);
    }
    __builtin_amdgcn_s_setprio(0);
    __syncthreads();
  }

  // epilogue: o rows are q = qbase + lk*4 + i; fetch l for those rows
  float linv[4];
#pragma unroll
  for (int i = 0; i < 4; ++i) {
    float lq = __shfl(l_i, lk * 4 + i);
    linv[i] = 1.0f / lq;
  }
#pragma unroll
  for (int t4 = 0; t4 < 4; ++t4) {
    int col = h * DK + t4 * 16 + l16;
#pragma unroll
    for (int i = 0; i < 4; ++i) {
      int srow_ = qbase + lk * 4 + i;
      AO[(size_t)(b * SEQ + srow_) * DMODEL + col] = f2bf(o[t4][i] * linv[i]);
    }
  }
}

extern "C" void kernel_launch(void* const* d_in, const int* in_sizes, int n_in,
                              void* d_out, int out_size, void* d_ws, size_t ws_size,
                              hipStream_t stream) {
  const float* gq  = (const float*)d_in[0];
  const float* gk  = (const float*)d_in[1];
  const float* gv  = (const float*)d_in[2];
  const int* gmask = (const int*)d_in[3];
  const float* gWq = (const float*)d_in[4];
  const float* gbq = (const float*)d_in[5];
  const float* gWk = (const float*)d_in[6];
  const float* gbk = (const float*)d_in[7];
  const float* gWv = (const float*)d_in[8];
  const float* gbv = (const float*)d_in[9];
  const float* gWo = (const float*)d_in[10];
  const float* gbo = (const float*)d_in[11];
  float* out = (float*)d_out;

  char* ws = (char*)d_ws;
  const size_t XSZ = (size_t)NTOK * DMODEL * 2;
  const size_t WSZ = (size_t)DMODEL * DMODEL * 2;
  unsigned short* Xq  = (unsigned short*)ws; ws += XSZ;
  unsigned short* Xk  = (unsigned short*)ws; ws += XSZ;
  unsigned short* Xv  = (unsigned short*)ws; ws += XSZ;
  unsigned short* WqT = (unsigned short*)ws; ws += WSZ;
  unsigned short* WkT = (unsigned short*)ws; ws += WSZ;
  unsigned short* WvT = (unsigned short*)ws; ws += WSZ;
  unsigned short* WoT = (unsigned short*)ws; ws += WSZ;
  unsigned short* Qh  = (unsigned short*)ws; ws += XSZ;
  unsigned short* Kh  = (unsigned short*)ws; ws += XSZ;
  unsigned short* Vh  = (unsigned short*)ws; ws += XSZ;
  unsigned short* Vt  = (unsigned short*)ws; ws += XSZ;
  unsigned short* AO  = (unsigned short*)ws; ws += XSZ;
  float* maskbias     = (float*)ws; ws += (size_t)NB * SEQ * 4;

  convx_kernel<<<dim3(NTOK * DMODEL / 1024, 1, 3), 256, 0, stream>>>(gq, gk, gv, Xq, Xk, Xv);
  wtrans_kernel<<<dim3(12, 12, 5), 256, 0, stream>>>(gWq, gWk, gWv, gWo, WqT, WkT, WvT, WoT,
                                                     gmask, maskbias);

  QKVArgs ga;
  ga.A[0] = Xq; ga.A[1] = Xk; ga.A[2] = Xv;
  ga.BT[0] = WqT; ga.BT[1] = WkT; ga.BT[2] = WvT;
  ga.bias[0] = gbq; ga.bias[1] = gbk; ga.bias[2] = gbv;
  ga.out[0] = Qh; ga.out[1] = Kh; ga.out[2] = Vh;
  ga.scale[0] = 0.18033688011112042f;  // 0.125 * log2(e)
  ga.scale[1] = 1.f; ga.scale[2] = 1.f;
  gemm_qkv_kernel<<<dim3(32, 6, 3), 256, 0, stream>>>(ga);

  vtrans_kernel<<<dim3(SEQ / 64, NB * NHEAD), 256, 0, stream>>>(Vh, Vt);
  flash_kernel<<<dim3(8 * 96), 256, 0, stream>>>(Qh, Kh, Vt, maskbias, AO);
  gemm_o_kernel<<<dim3(32, 6), 256, 0, stream>>>(AO, WoT, gbo, out);
}